// Round 21
// baseline (28.118 us; speedup 1.0000x reference)
//
#include <hip/hip_runtime.h>
#include <math.h>

#define NB 2
#define NN 1024
#define NH 64
#define NK 8
#define ITILE 16

typedef float f32x2 __attribute__((ext_vector_type(2)));
typedef float f32x16 __attribute__((ext_vector_type(16)));
typedef _Float16 half8 __attribute__((ext_vector_type(8)));
typedef _Float16 half2t __attribute__((ext_vector_type(2)));
typedef __fp16 fp16x2 __attribute__((ext_vector_type(2)));
typedef unsigned u32x2 __attribute__((ext_vector_type(2)));

union FragU { uint32_t u[4]; uint4 q; half8 h; };
union H2U  { half2t h; fp16x2 p; uint32_t u; };
union C32U { f32x16 v; f32x2 d[8]; float f[16]; };

static __device__ __forceinline__ uint32_t pk_rne(float a, float b) {
    half2t t; t[0] = (_Float16)a; t[1] = (_Float16)b;
    H2U r; r.h = t; return r.u;
}

// cross-half sum without DS: own + partner(lane^32), pure VALU
static __device__ __forceinline__ float wave_sum_half(float v) {
#if __has_builtin(__builtin_amdgcn_permlane32_swap)
    union { float f; uint32_t u; } a, r0, r1;
    a.f = v;
    u32x2 s = __builtin_amdgcn_permlane32_swap(a.u, a.u, false, false);
    r0.u = s[0]; r1.u = s[1];
    return r0.f + r1.f;
#else
    return v + __shfl_xor(v, 32);
#endif
}

// ---------------- single fused kernel ----------------
// r20 structure (ITILE=16, permuted-A2 GEMM2, single chained acc).
// Changes: #pragma unroll 8 (deeper cross-iter scheduling); waves_per_eu
// attribute dropped (neutral in r17 A/B; frees regalloc under unroll 8).
__global__ __launch_bounds__(256, 4)
void rpe_kernel(
    const float* __restrict__ rv,
    const float* __restrict__ W1,
    const float* __restrict__ b1,
    const float* __restrict__ W2,
    const float* __restrict__ gamma,
    const float* __restrict__ beta,
    const float* __restrict__ b2,
    float* __restrict__ out) {
    __shared__ uint4 qlds[ITILE * 2 * 64];   // 32768 B
    __shared__ float w1t[NH][6];             // 1536 B
    __shared__ float w2g[NH * NK];           // 2048 B
    __shared__ float meanS[6];
    __shared__ int oks;

    const int tid  = threadIdx.x;
    const int wave = tid >> 6;
    const int lane = tid & 63;
    const int jj   = lane & 31;
    const int hi   = lane >> 5;
    const int b  = blockIdx.z;
    const int j0 = blockIdx.x * 128 + wave * 32;
    const int iBase = blockIdx.y * ITILE;

    const float4* rv4 = reinterpret_cast<const float4*>(rv);
    const float4* rvb = rv4 + b*NN + iBase;

    // ---- phase -1a: column means via wave shuffle-reduce ----
    if (tid == 0) oks = 1;
    {
        float m1 = (wave < 4) ? W1[wave*NH + lane] : 0.f;
#pragma unroll
        for (int off = 1; off < 64; off <<= 1) m1 += __shfl_xor(m1, off);
        if (lane == 0 && wave < 4) meanS[wave] = m1 * (1.f/NH);
        float m2 = 0.f;
        if (wave == 0) m2 = W1[4*NH + lane];
        else if (wave == 1) m2 = b1[lane];
#pragma unroll
        for (int off = 1; off < 64; off <<= 1) m2 += __shfl_xor(m2, off);
        if (lane == 0 && wave == 0) meanS[4] = m2 * (1.f/NH);
        if (lane == 0 && wave == 1) meanS[5] = m2 * (1.f/NH);
    }
    __syncthreads();
    // ---- phase -1b: fast-flag check ----
    if (tid < NH) {
        if (!(beta[tid] == 0.f && gamma[tid] >= 0.f)) atomicAnd(&oks, 0);
    }
    __syncthreads();
    const int fast = oks;
    // ---- phase -1c: tables ----
    if (tid < NH) {
        const int h = tid;
        const float gh = fast ? gamma[h] : 1.f;
#pragma unroll
        for (int k = 0; k < NK; ++k) w2g[h*NK + k] = W2[h*NK + k] * gh;
        w1t[h][0] = W1[0*NH+h] - meanS[0];
        w1t[h][1] = W1[1*NH+h] - meanS[1];
        w1t[h][2] = W1[2*NH+h] - meanS[2];
        w1t[h][3] = W1[3*NH+h] - meanS[3];
        w1t[h][4] = W1[4*NH+h] - meanS[4];
        w1t[h][5] = b1[h] - meanS[5];
    }
    __syncthreads();

    // ---- permuted A2 fragments: chunk c, lane (g,row): reg t holds
    //      h_lo = 16c + {0,2,8,10}[t] + 4g, h_hi = h_lo + 1
    FragU a2[4];
    {
        const int row = lane & 31;
        const int g   = lane >> 5;
        const int hml[4] = {0, 2, 8, 10};
#pragma unroll
        for (int c = 0; c < 4; ++c) {
#pragma unroll
            for (int t = 0; t < 4; ++t) {
                const int h_lo = 16*c + hml[t] + 4*g;
                const float a = (row < 8) ? w2g[h_lo*NK + row]       : 0.f;
                const float d = (row < 8) ? w2g[(h_lo+1)*NK + row]   : 0.f;
                a2[c].u[t] = pk_rne(a, d);
            }
        }
    }

    // ---- phase 0: cooperative A1-frag build from rv (2 i per thread) ----
    {
        const int it = tid >> 5;         // 0..7
        const int sl = tid & 31;         // row slot 0..31
#pragma unroll
        for (int rep = 0; rep < 2; ++rep) {
            const int i2 = it + rep * 8;           // 0..15
            const float4 p = rvb[i2];
            const float x0 = p.x, y0 = p.y;
            const float vx = p.z - x0, vy = p.w - y0;
            const float rinv = rsqrtf(fmaf(vx, vx, vy * vy));
            const float ci = vx * rinv, si = vy * rinv;
            const float u1 = fmaf(x0, ci, y0 * si);
            const float u2 = fmaf(y0, ci, -x0 * si);
#pragma unroll
            for (int T = 0; T < 2; ++T) {
                const int h = 32*T + sl;
                const float w0v = w1t[h][0], w1v = w1t[h][1], w2v = w1t[h][2];
                const float w3v = w1t[h][3], w4v = w1t[h][4], bbc = w1t[h][5];
                const float qc = fmaf(w1v, ci,  w2v * si);
                const float qs = fmaf(w1v, si, -w2v * ci);
                const float qx = fmaf(-w3v, ci,  w4v * si);
                const float qy = fmaf(-w3v, si, -w4v * ci);
                const float cn = fmaf(w3v, u1, fmaf(w4v, u2, bbc));
                H2U a_, b_, c_;
                a_.p = __builtin_amdgcn_cvt_pkrtz(qc, qs);
                b_.p = __builtin_amdgcn_cvt_pkrtz(qx, qy);
                c_.p = __builtin_amdgcn_cvt_pkrtz(w0v, cn);
                uint4 v; v.x = a_.u; v.y = b_.u; v.z = c_.u; v.w = 0u;
                qlds[(i2*2+T)*64 + sl]      = v;
                qlds[(i2*2+T)*64 + 32 + sl] = make_uint4(0,0,0,0);  // hi k-slots zero
            }
        }
    }
    __syncthreads();

    // ---- per-j statics from rv ----
    const float4 pj = rv4[b*NN + j0 + jj];
    const float xj = pj.x, yj = pj.y;
    const float vxj = pj.z - xj, vyj = pj.w - yj;
    const float rinvj = rsqrtf(fmaf(vxj, vxj, vyj * vyj));
    H2U d0u, d1u;
    d0u.p = __builtin_amdgcn_cvt_pkrtz(vxj * rinvj, vyj * rinvj);
    d1u.p = __builtin_amdgcn_cvt_pkrtz(xj, yj);
    const uint32_t d0 = d0u.u, d1 = d1u.u;

    float b2v[4];
#pragma unroll
    for (int r = 0; r < 4; ++r) b2v[r] = b2[4*hi + r];

    const f32x16 z16 = {0,0,0,0,0,0,0,0,0,0,0,0,0,0,0,0};
    half2t z2h; z2h[0] = (_Float16)0.f; z2h[1] = (_Float16)0.f;
    const size_t plane = (size_t)NN * NN;
    float* o0 = out + (size_t)(b*NK + 4*hi)*plane + (size_t)iBase*NN + (j0 + jj);
    float* o1 = o0 + plane;
    float* o2 = o0 + 2*plane;
    float* o3 = o0 + 3*plane;

    if (fast) {
#pragma unroll 8
        for (int ii = 0; ii < ITILE; ++ii) {
            FragU qf0, qf1;
            qf0.q = qlds[(ii*2+0)*64 + lane];
            qf1.q = qlds[(ii*2+1)*64 + lane];
            const float4 piv = rvb[ii];

            const float dx = piv.x - xj, dy = piv.y - yj;
            const float dist = __builtin_amdgcn_sqrtf(fmaf(dx, dx, dy * dy));
            const float g32 = 0.69314718f * __builtin_amdgcn_logf(dist + 1e-5f);
            H2U e0; e0.p = __builtin_amdgcn_cvt_pkrtz(g32, 1.0f);
            FragU bf; bf.u[0] = d0; bf.u[1] = d1; bf.u[2] = e0.u; bf.u[3] = 0u;

            C32U cA, cB;
            cA.v = __builtin_amdgcn_mfma_f32_32x32x16_f16(qf0.h, bf.h, z16, 0, 0, 0);
            cB.v = __builtin_amdgcn_mfma_f32_32x32x16_f16(qf1.h, bf.h, z16, 0, 0, 0);

            // variance (mu==0 exact): sumsq, off the MFMA2 path
            f32x2 q0 = cA.d[0]*cA.d[0], q1 = cA.d[1]*cA.d[1], q2 = cA.d[2]*cA.d[2], q3 = cA.d[3]*cA.d[3];
            q0 = __builtin_elementwise_fma(cA.d[4], cA.d[4], q0);
            q1 = __builtin_elementwise_fma(cA.d[5], cA.d[5], q1);
            q2 = __builtin_elementwise_fma(cA.d[6], cA.d[6], q2);
            q3 = __builtin_elementwise_fma(cA.d[7], cA.d[7], q3);
            q0 = __builtin_elementwise_fma(cB.d[0], cB.d[0], q0);
            q1 = __builtin_elementwise_fma(cB.d[1], cB.d[1], q1);
            q2 = __builtin_elementwise_fma(cB.d[2], cB.d[2], q2);
            q3 = __builtin_elementwise_fma(cB.d[3], cB.d[3], q3);
            q0 = __builtin_elementwise_fma(cB.d[4], cB.d[4], q0);
            q1 = __builtin_elementwise_fma(cB.d[5], cB.d[5], q1);
            q2 = __builtin_elementwise_fma(cB.d[6], cB.d[6], q2);
            q3 = __builtin_elementwise_fma(cB.d[7], cB.d[7], q3);
            q0 += q1; q2 += q3; q0 += q2;
            float sq = q0[0] + q0[1];
            sq = wave_sum_half(sq);
            const float inv = __builtin_amdgcn_rsqf(fmaf(sq, 1.f/64.f, 1e-5f));

            // pack then relu in packed f16 (independent of inv)
            uint32_t yw[16];
#pragma unroll
            for (int m = 0; m < 8; ++m) {
                H2U t; t.p = __builtin_amdgcn_cvt_pkrtz(cA.d[m][0], cA.d[m][1]);
                half2t r = __builtin_elementwise_max(t.h, z2h);
                H2U o; o.h = r; yw[m] = o.u;
            }
#pragma unroll
            for (int m = 0; m < 8; ++m) {
                H2U t; t.p = __builtin_amdgcn_cvt_pkrtz(cB.d[m][0], cB.d[m][1]);
                half2t r = __builtin_elementwise_max(t.h, z2h);
                H2U o; o.h = r; yw[8+m] = o.u;
            }

            // GEMM2: yw words ARE the B-frags (permuted A2); one chained acc
            C32U acc; acc.v = z16;
#pragma unroll
            for (int c = 0; c < 4; ++c) {
                FragU Bf; Bf.u[0] = yw[4*c+0]; Bf.u[1] = yw[4*c+1];
                Bf.u[2] = yw[4*c+2]; Bf.u[3] = yw[4*c+3];
                acc.v = __builtin_amdgcn_mfma_f32_32x32x16_f16(a2[c].h, Bf.h, acc.v, 0, 0, 0);
            }

            o0[0] = fmaf(acc.f[0], inv, b2v[0]);
            o1[0] = fmaf(acc.f[1], inv, b2v[1]);
            o2[0] = fmaf(acc.f[2], inv, b2v[2]);
            o3[0] = fmaf(acc.f[3], inv, b2v[3]);
            o0 += NN; o1 += NN; o2 += NN; o3 += NN;
        }
    } else {
        // general fallback: full normalize with gamma/beta (inline loads)
        for (int ii = 0; ii < ITILE; ++ii) {
            FragU qf0, qf1;
            qf0.q = qlds[(ii*2+0)*64 + lane];
            qf1.q = qlds[(ii*2+1)*64 + lane];
            const float4 piv = rvb[ii];

            const float dx = piv.x - xj, dy = piv.y - yj;
            const float dist = __builtin_amdgcn_sqrtf(fmaf(dx, dx, dy * dy));
            const float g32 = 0.69314718f * __builtin_amdgcn_logf(dist + 1e-5f);
            H2U e0; e0.p = __builtin_amdgcn_cvt_pkrtz(g32, 1.0f);
            FragU bf; bf.u[0] = d0; bf.u[1] = d1; bf.u[2] = e0.u; bf.u[3] = 0u;

            C32U cA, cB;
            cA.v = __builtin_amdgcn_mfma_f32_32x32x16_f16(qf0.h, bf.h, z16, 0, 0, 0);
            cB.v = __builtin_amdgcn_mfma_f32_32x32x16_f16(qf1.h, bf.h, z16, 0, 0, 0);

            f32x2 q0 = cA.d[0]*cA.d[0], q1 = cA.d[1]*cA.d[1], q2 = cA.d[2]*cA.d[2], q3 = cA.d[3]*cA.d[3];
            q0 = __builtin_elementwise_fma(cA.d[4], cA.d[4], q0);
            q1 = __builtin_elementwise_fma(cA.d[5], cA.d[5], q1);
            q2 = __builtin_elementwise_fma(cA.d[6], cA.d[6], q2);
            q3 = __builtin_elementwise_fma(cA.d[7], cA.d[7], q3);
            q0 = __builtin_elementwise_fma(cB.d[0], cB.d[0], q0);
            q1 = __builtin_elementwise_fma(cB.d[1], cB.d[1], q1);
            q2 = __builtin_elementwise_fma(cB.d[2], cB.d[2], q2);
            q3 = __builtin_elementwise_fma(cB.d[3], cB.d[3], q3);
            q0 = __builtin_elementwise_fma(cB.d[4], cB.d[4], q0);
            q1 = __builtin_elementwise_fma(cB.d[5], cB.d[5], q1);
            q2 = __builtin_elementwise_fma(cB.d[6], cB.d[6], q2);
            q3 = __builtin_elementwise_fma(cB.d[7], cB.d[7], q3);
            q0 += q1; q2 += q3; q0 += q2;
            float sq = q0[0] + q0[1];
            sq = wave_sum_half(sq);
            const float inv = __builtin_amdgcn_rsqf(fmaf(sq, 1.f/64.f, 1e-5f));
            H2U inv2u; inv2u.p = __builtin_amdgcn_cvt_pkrtz(inv, inv);
            const half2t inv2 = inv2u.h;

            uint32_t yw[16];
#pragma unroll
            for (int m = 0; m < 16; ++m) {
                const f32x2 src = (m < 8) ? cA.d[m] : cB.d[m - 8];
                const int T = m >> 3, mm = m & 7;
                const int h0 = 32*T + 8*(mm>>1) + 2*(mm&1) + 4*hi;
                H2U x; x.p = __builtin_amdgcn_cvt_pkrtz(src[0], src[1]);
                H2U gg, bb;
                gg.u = pk_rne(gamma[h0], gamma[h0+1]);
                bb.u = pk_rne(beta[h0],  beta[h0+1]);
                half2t gs = gg.h * inv2;
                half2t y = __builtin_elementwise_fma(x.h, gs, bb.h);
                y = __builtin_elementwise_max(y, z2h);
                H2U o; o.h = y; yw[m] = o.u;
            }

            C32U acc; acc.v = z16;
#pragma unroll
            for (int c = 0; c < 4; ++c) {
                FragU Bf; Bf.u[0] = yw[4*c+0]; Bf.u[1] = yw[4*c+1];
                Bf.u[2] = yw[4*c+2]; Bf.u[3] = yw[4*c+3];
                acc.v = __builtin_amdgcn_mfma_f32_32x32x16_f16(a2[c].h, Bf.h, acc.v, 0, 0, 0);
            }

            o0[0] = acc.f[0] + b2v[0];
            o1[0] = acc.f[1] + b2v[1];
            o2[0] = acc.f[2] + b2v[2];
            o3[0] = acc.f[3] + b2v[3];
            o0 += NN; o1 += NN; o2 += NN; o3 += NN;
        }
    }
}

extern "C" void kernel_launch(void* const* d_in, const int* in_sizes, int n_in,
                              void* d_out, int out_size, void* d_ws, size_t ws_size,
                              hipStream_t stream) {
    const float* rv    = (const float*)d_in[0];
    const float* W1    = (const float*)d_in[1];
    const float* b1    = (const float*)d_in[2];
    const float* gamma = (const float*)d_in[3];
    const float* beta  = (const float*)d_in[4];
    const float* W2    = (const float*)d_in[5];
    const float* b2    = (const float*)d_in[6];
    float* out = (float*)d_out;

    dim3 grid(NN / 128, NN / ITILE, NB);
    rpe_kernel<<<grid, 256, 0, stream>>>(rv, W1, b1, W2, gamma, beta, b2, out);
}

// Round 22
// 27.995 us; speedup vs baseline: 1.0044x; 1.0044x over previous
//
#include <hip/hip_runtime.h>
#include <math.h>

#define NB 2
#define NN 1024
#define NH 64
#define NK 8
#define ITILE 16

typedef float f32x2 __attribute__((ext_vector_type(2)));
typedef float f32x16 __attribute__((ext_vector_type(16)));
typedef _Float16 half8 __attribute__((ext_vector_type(8)));
typedef _Float16 half2t __attribute__((ext_vector_type(2)));
typedef __fp16 fp16x2 __attribute__((ext_vector_type(2)));
typedef unsigned u32x2 __attribute__((ext_vector_type(2)));

union FragU { uint32_t u[4]; uint4 q; half8 h; };
union H2U  { half2t h; fp16x2 p; uint32_t u; };
union C32U { f32x16 v; f32x2 d[8]; float f[16]; };

static __device__ __forceinline__ uint32_t pk_rne(float a, float b) {
    half2t t; t[0] = (_Float16)a; t[1] = (_Float16)b;
    H2U r; r.h = t; return r.u;
}

// cross-half sum without DS: own + partner(lane^32), pure VALU
static __device__ __forceinline__ float wave_sum_half(float v) {
#if __has_builtin(__builtin_amdgcn_permlane32_swap)
    union { float f; uint32_t u; } a, r0, r1;
    a.f = v;
    u32x2 s = __builtin_amdgcn_permlane32_swap(a.u, a.u, false, false);
    r0.u = s[0]; r1.u = s[1];
    return r0.f + r1.f;
#else
    return v + __shfl_xor(v, 32);
#endif
}

// ---------------- single fused kernel ----------------
// r20 best-measured config restored (unroll 4, waves_per_eu(4,4)).
// NEW: per-i (x0,y0) stashed in LDS during phase 0 -> the per-iter
// 16B uniform global load (L2 ~200cy, feeds the serial feature chain)
// becomes an 8B ds_read (~120cy). Loop math frozen (r15 lineage).
__global__ __launch_bounds__(256, 4)
__attribute__((amdgpu_waves_per_eu(4, 4)))
void rpe_kernel(
    const float* __restrict__ rv,
    const float* __restrict__ W1,
    const float* __restrict__ b1,
    const float* __restrict__ W2,
    const float* __restrict__ gamma,
    const float* __restrict__ beta,
    const float* __restrict__ b2,
    float* __restrict__ out) {
    __shared__ uint4 qlds[ITILE * 2 * 64];   // 32768 B
    __shared__ float w1t[NH][6];             // 1536 B
    __shared__ float w2g[NH * NK];           // 2048 B
    __shared__ float xyt[ITILE][2];          // 128 B  (x0,y0 per i)
    __shared__ float meanS[6];
    __shared__ int oks;

    const int tid  = threadIdx.x;
    const int wave = tid >> 6;
    const int lane = tid & 63;
    const int jj   = lane & 31;
    const int hi   = lane >> 5;
    const int b  = blockIdx.z;
    const int j0 = blockIdx.x * 128 + wave * 32;
    const int iBase = blockIdx.y * ITILE;

    const float4* rv4 = reinterpret_cast<const float4*>(rv);
    const float4* rvb = rv4 + b*NN + iBase;

    // ---- phase -1a: column means via wave shuffle-reduce ----
    if (tid == 0) oks = 1;
    {
        float m1 = (wave < 4) ? W1[wave*NH + lane] : 0.f;
#pragma unroll
        for (int off = 1; off < 64; off <<= 1) m1 += __shfl_xor(m1, off);
        if (lane == 0 && wave < 4) meanS[wave] = m1 * (1.f/NH);
        float m2 = 0.f;
        if (wave == 0) m2 = W1[4*NH + lane];
        else if (wave == 1) m2 = b1[lane];
#pragma unroll
        for (int off = 1; off < 64; off <<= 1) m2 += __shfl_xor(m2, off);
        if (lane == 0 && wave == 0) meanS[4] = m2 * (1.f/NH);
        if (lane == 0 && wave == 1) meanS[5] = m2 * (1.f/NH);
    }
    __syncthreads();
    // ---- phase -1b: fast-flag check ----
    if (tid < NH) {
        if (!(beta[tid] == 0.f && gamma[tid] >= 0.f)) atomicAnd(&oks, 0);
    }
    __syncthreads();
    const int fast = oks;
    // ---- phase -1c: tables ----
    if (tid < NH) {
        const int h = tid;
        const float gh = fast ? gamma[h] : 1.f;
#pragma unroll
        for (int k = 0; k < NK; ++k) w2g[h*NK + k] = W2[h*NK + k] * gh;
        w1t[h][0] = W1[0*NH+h] - meanS[0];
        w1t[h][1] = W1[1*NH+h] - meanS[1];
        w1t[h][2] = W1[2*NH+h] - meanS[2];
        w1t[h][3] = W1[3*NH+h] - meanS[3];
        w1t[h][4] = W1[4*NH+h] - meanS[4];
        w1t[h][5] = b1[h] - meanS[5];
    }
    __syncthreads();

    // ---- permuted A2 fragments: chunk c, lane (g,row): reg t holds
    //      h_lo = 16c + {0,2,8,10}[t] + 4g, h_hi = h_lo + 1
    FragU a2[4];
    {
        const int row = lane & 31;
        const int g   = lane >> 5;
        const int hml[4] = {0, 2, 8, 10};
#pragma unroll
        for (int c = 0; c < 4; ++c) {
#pragma unroll
            for (int t = 0; t < 4; ++t) {
                const int h_lo = 16*c + hml[t] + 4*g;
                const float a = (row < 8) ? w2g[h_lo*NK + row]       : 0.f;
                const float d = (row < 8) ? w2g[(h_lo+1)*NK + row]   : 0.f;
                a2[c].u[t] = pk_rne(a, d);
            }
        }
    }

    // ---- phase 0: cooperative A1-frag build from rv (2 i per thread) ----
    {
        const int it = tid >> 5;         // 0..7
        const int sl = tid & 31;         // row slot 0..31
#pragma unroll
        for (int rep = 0; rep < 2; ++rep) {
            const int i2 = it + rep * 8;           // 0..15
            const float4 p = rvb[i2];
            const float x0 = p.x, y0 = p.y;
            const float vx = p.z - x0, vy = p.w - y0;
            const float rinv = rsqrtf(fmaf(vx, vx, vy * vy));
            const float ci = vx * rinv, si = vy * rinv;
            const float u1 = fmaf(x0, ci, y0 * si);
            const float u2 = fmaf(y0, ci, -x0 * si);
            if (sl == 0) { xyt[i2][0] = x0; xyt[i2][1] = y0; }
#pragma unroll
            for (int T = 0; T < 2; ++T) {
                const int h = 32*T + sl;
                const float w0v = w1t[h][0], w1v = w1t[h][1], w2v = w1t[h][2];
                const float w3v = w1t[h][3], w4v = w1t[h][4], bbc = w1t[h][5];
                const float qc = fmaf(w1v, ci,  w2v * si);
                const float qs = fmaf(w1v, si, -w2v * ci);
                const float qx = fmaf(-w3v, ci,  w4v * si);
                const float qy = fmaf(-w3v, si, -w4v * ci);
                const float cn = fmaf(w3v, u1, fmaf(w4v, u2, bbc));
                H2U a_, b_, c_;
                a_.p = __builtin_amdgcn_cvt_pkrtz(qc, qs);
                b_.p = __builtin_amdgcn_cvt_pkrtz(qx, qy);
                c_.p = __builtin_amdgcn_cvt_pkrtz(w0v, cn);
                uint4 v; v.x = a_.u; v.y = b_.u; v.z = c_.u; v.w = 0u;
                qlds[(i2*2+T)*64 + sl]      = v;
                qlds[(i2*2+T)*64 + 32 + sl] = make_uint4(0,0,0,0);  // hi k-slots zero
            }
        }
    }
    __syncthreads();

    // ---- per-j statics from rv ----
    const float4 pj = rv4[b*NN + j0 + jj];
    const float xj = pj.x, yj = pj.y;
    const float vxj = pj.z - xj, vyj = pj.w - yj;
    const float rinvj = rsqrtf(fmaf(vxj, vxj, vyj * vyj));
    H2U d0u, d1u;
    d0u.p = __builtin_amdgcn_cvt_pkrtz(vxj * rinvj, vyj * rinvj);
    d1u.p = __builtin_amdgcn_cvt_pkrtz(xj, yj);
    const uint32_t d0 = d0u.u, d1 = d1u.u;

    float b2v[4];
#pragma unroll
    for (int r = 0; r < 4; ++r) b2v[r] = b2[4*hi + r];

    const f32x16 z16 = {0,0,0,0,0,0,0,0,0,0,0,0,0,0,0,0};
    half2t z2h; z2h[0] = (_Float16)0.f; z2h[1] = (_Float16)0.f;
    const size_t plane = (size_t)NN * NN;
    float* o0 = out + (size_t)(b*NK + 4*hi)*plane + (size_t)iBase*NN + (j0 + jj);
    float* o1 = o0 + plane;
    float* o2 = o0 + 2*plane;
    float* o3 = o0 + 3*plane;

    if (fast) {
#pragma unroll 4
        for (int ii = 0; ii < ITILE; ++ii) {
            FragU qf0, qf1;
            qf0.q = qlds[(ii*2+0)*64 + lane];
            qf1.q = qlds[(ii*2+1)*64 + lane];
            const float2 pxy = *reinterpret_cast<const float2*>(&xyt[ii][0]);

            const float dx = pxy.x - xj, dy = pxy.y - yj;
            const float dist = __builtin_amdgcn_sqrtf(fmaf(dx, dx, dy * dy));
            const float g32 = 0.69314718f * __builtin_amdgcn_logf(dist + 1e-5f);
            H2U e0; e0.p = __builtin_amdgcn_cvt_pkrtz(g32, 1.0f);
            FragU bf; bf.u[0] = d0; bf.u[1] = d1; bf.u[2] = e0.u; bf.u[3] = 0u;

            C32U cA, cB;
            cA.v = __builtin_amdgcn_mfma_f32_32x32x16_f16(qf0.h, bf.h, z16, 0, 0, 0);
            cB.v = __builtin_amdgcn_mfma_f32_32x32x16_f16(qf1.h, bf.h, z16, 0, 0, 0);

            // variance (mu==0 exact): sumsq, off the MFMA2 path
            f32x2 q0 = cA.d[0]*cA.d[0], q1 = cA.d[1]*cA.d[1], q2 = cA.d[2]*cA.d[2], q3 = cA.d[3]*cA.d[3];
            q0 = __builtin_elementwise_fma(cA.d[4], cA.d[4], q0);
            q1 = __builtin_elementwise_fma(cA.d[5], cA.d[5], q1);
            q2 = __builtin_elementwise_fma(cA.d[6], cA.d[6], q2);
            q3 = __builtin_elementwise_fma(cA.d[7], cA.d[7], q3);
            q0 = __builtin_elementwise_fma(cB.d[0], cB.d[0], q0);
            q1 = __builtin_elementwise_fma(cB.d[1], cB.d[1], q1);
            q2 = __builtin_elementwise_fma(cB.d[2], cB.d[2], q2);
            q3 = __builtin_elementwise_fma(cB.d[3], cB.d[3], q3);
            q0 = __builtin_elementwise_fma(cB.d[4], cB.d[4], q0);
            q1 = __builtin_elementwise_fma(cB.d[5], cB.d[5], q1);
            q2 = __builtin_elementwise_fma(cB.d[6], cB.d[6], q2);
            q3 = __builtin_elementwise_fma(cB.d[7], cB.d[7], q3);
            q0 += q1; q2 += q3; q0 += q2;
            float sq = q0[0] + q0[1];
            sq = wave_sum_half(sq);
            const float inv = __builtin_amdgcn_rsqf(fmaf(sq, 1.f/64.f, 1e-5f));

            // pack then relu in packed f16 (independent of inv)
            uint32_t yw[16];
#pragma unroll
            for (int m = 0; m < 8; ++m) {
                H2U t; t.p = __builtin_amdgcn_cvt_pkrtz(cA.d[m][0], cA.d[m][1]);
                half2t r = __builtin_elementwise_max(t.h, z2h);
                H2U o; o.h = r; yw[m] = o.u;
            }
#pragma unroll
            for (int m = 0; m < 8; ++m) {
                H2U t; t.p = __builtin_amdgcn_cvt_pkrtz(cB.d[m][0], cB.d[m][1]);
                half2t r = __builtin_elementwise_max(t.h, z2h);
                H2U o; o.h = r; yw[8+m] = o.u;
            }

            // GEMM2: yw words ARE the B-frags (permuted A2); one chained acc
            C32U acc; acc.v = z16;
#pragma unroll
            for (int c = 0; c < 4; ++c) {
                FragU Bf; Bf.u[0] = yw[4*c+0]; Bf.u[1] = yw[4*c+1];
                Bf.u[2] = yw[4*c+2]; Bf.u[3] = yw[4*c+3];
                acc.v = __builtin_amdgcn_mfma_f32_32x32x16_f16(a2[c].h, Bf.h, acc.v, 0, 0, 0);
            }

            o0[0] = fmaf(acc.f[0], inv, b2v[0]);
            o1[0] = fmaf(acc.f[1], inv, b2v[1]);
            o2[0] = fmaf(acc.f[2], inv, b2v[2]);
            o3[0] = fmaf(acc.f[3], inv, b2v[3]);
            o0 += NN; o1 += NN; o2 += NN; o3 += NN;
        }
    } else {
        // general fallback: full normalize with gamma/beta (inline loads)
        for (int ii = 0; ii < ITILE; ++ii) {
            FragU qf0, qf1;
            qf0.q = qlds[(ii*2+0)*64 + lane];
            qf1.q = qlds[(ii*2+1)*64 + lane];
            const float2 pxy = *reinterpret_cast<const float2*>(&xyt[ii][0]);

            const float dx = pxy.x - xj, dy = pxy.y - yj;
            const float dist = __builtin_amdgcn_sqrtf(fmaf(dx, dx, dy * dy));
            const float g32 = 0.69314718f * __builtin_amdgcn_logf(dist + 1e-5f);
            H2U e0; e0.p = __builtin_amdgcn_cvt_pkrtz(g32, 1.0f);
            FragU bf; bf.u[0] = d0; bf.u[1] = d1; bf.u[2] = e0.u; bf.u[3] = 0u;

            C32U cA, cB;
            cA.v = __builtin_amdgcn_mfma_f32_32x32x16_f16(qf0.h, bf.h, z16, 0, 0, 0);
            cB.v = __builtin_amdgcn_mfma_f32_32x32x16_f16(qf1.h, bf.h, z16, 0, 0, 0);

            f32x2 q0 = cA.d[0]*cA.d[0], q1 = cA.d[1]*cA.d[1], q2 = cA.d[2]*cA.d[2], q3 = cA.d[3]*cA.d[3];
            q0 = __builtin_elementwise_fma(cA.d[4], cA.d[4], q0);
            q1 = __builtin_elementwise_fma(cA.d[5], cA.d[5], q1);
            q2 = __builtin_elementwise_fma(cA.d[6], cA.d[6], q2);
            q3 = __builtin_elementwise_fma(cA.d[7], cA.d[7], q3);
            q0 = __builtin_elementwise_fma(cB.d[0], cB.d[0], q0);
            q1 = __builtin_elementwise_fma(cB.d[1], cB.d[1], q1);
            q2 = __builtin_elementwise_fma(cB.d[2], cB.d[2], q2);
            q3 = __builtin_elementwise_fma(cB.d[3], cB.d[3], q3);
            q0 = __builtin_elementwise_fma(cB.d[4], cB.d[4], q0);
            q1 = __builtin_elementwise_fma(cB.d[5], cB.d[5], q1);
            q2 = __builtin_elementwise_fma(cB.d[6], cB.d[6], q2);
            q3 = __builtin_elementwise_fma(cB.d[7], cB.d[7], q3);
            q0 += q1; q2 += q3; q0 += q2;
            float sq = q0[0] + q0[1];
            sq = wave_sum_half(sq);
            const float inv = __builtin_amdgcn_rsqf(fmaf(sq, 1.f/64.f, 1e-5f));
            H2U inv2u; inv2u.p = __builtin_amdgcn_cvt_pkrtz(inv, inv);
            const half2t inv2 = inv2u.h;

            uint32_t yw[16];
#pragma unroll
            for (int m = 0; m < 16; ++m) {
                const f32x2 src = (m < 8) ? cA.d[m] : cB.d[m - 8];
                const int T = m >> 3, mm = m & 7;
                const int h0 = 32*T + 8*(mm>>1) + 2*(mm&1) + 4*hi;
                H2U x; x.p = __builtin_amdgcn_cvt_pkrtz(src[0], src[1]);
                H2U gg, bb;
                gg.u = pk_rne(gamma[h0], gamma[h0+1]);
                bb.u = pk_rne(beta[h0],  beta[h0+1]);
                half2t gs = gg.h * inv2;
                half2t y = __builtin_elementwise_fma(x.h, gs, bb.h);
                y = __builtin_elementwise_max(y, z2h);
                H2U o; o.h = y; yw[m] = o.u;
            }

            C32U acc; acc.v = z16;
#pragma unroll
            for (int c = 0; c < 4; ++c) {
                FragU Bf; Bf.u[0] = yw[4*c+0]; Bf.u[1] = yw[4*c+1];
                Bf.u[2] = yw[4*c+2]; Bf.u[3] = yw[4*c+3];
                acc.v = __builtin_amdgcn_mfma_f32_32x32x16_f16(a2[c].h, Bf.h, acc.v, 0, 0, 0);
            }

            o0[0] = acc.f[0] + b2v[0];
            o1[0] = acc.f[1] + b2v[1];
            o2[0] = acc.f[2] + b2v[2];
            o3[0] = acc.f[3] + b2v[3];
            o0 += NN; o1 += NN; o2 += NN; o3 += NN;
        }
    }
}

extern "C" void kernel_launch(void* const* d_in, const int* in_sizes, int n_in,
                              void* d_out, int out_size, void* d_ws, size_t ws_size,
                              hipStream_t stream) {
    const float* rv    = (const float*)d_in[0];
    const float* W1    = (const float*)d_in[1];
    const float* b1    = (const float*)d_in[2];
    const float* gamma = (const float*)d_in[3];
    const float* beta  = (const float*)d_in[4];
    const float* W2    = (const float*)d_in[5];
    const float* b2    = (const float*)d_in[6];
    float* out = (float*)d_out;

    dim3 grid(NN / 128, NN / ITILE, NB);
    rpe_kernel<<<grid, 256, 0, stream>>>(rv, W1, b1, W2, gamma, beta, b2, out);
}